// Round 11
// baseline (103.304 us; speedup 1.0000x reference)
//
#include <hip/hip_runtime.h>
#include <hip/hip_bf16.h>

#define NN 20000
#define EE 160000
#define HH 32
#define MIDD 32

typedef _Float16 f16x4 __attribute__((ext_vector_type(4)));
typedef _Float16 f16x8 __attribute__((ext_vector_type(8)));
typedef float f32x4 __attribute__((ext_vector_type(4)));

__device__ __forceinline__ float silu_f(float v) {
    return __fdividef(v, 1.0f + __expf(-v));
}

// async global->LDS, 4B per lane; LDS dest = wave-uniform base + 4*lane.
__device__ __forceinline__ void gload_lds_b32(const void* gsrc, void* ldst) {
    __builtin_amdgcn_global_load_lds(
        (const __attribute__((address_space(1))) void*)gsrc,
        (__attribute__((address_space(3))) void*)ldst, 4, 0, 0);
}

// ---------------- prep kernels ----------------

__global__ void count_kernel(const int* __restrict__ ei, int* __restrict__ cnt) {
    int e = blockIdx.x * 256 + threadIdx.x;
    if (e < EE) atomicAdd(&cnt[ei[EE + e]], 1);
}

// Vectorized single-block scan (round-10 verified).
__global__ __launch_bounds__(1024) void scan_kernel(
    const int* __restrict__ cnt, int* __restrict__ off,
    int* __restrict__ cur, float* __restrict__ invc) {
    const int t = threadIdx.x;
    const int base = t * 20;
    __shared__ int wtot[16];

    int c[20];
    if (base + 20 <= NN) {
        const int4* p = (const int4*)(cnt + base);
        #pragma unroll
        for (int q = 0; q < 5; ++q) *(int4*)&c[4 * q] = p[q];
    } else {
        #pragma unroll
        for (int r = 0; r < 20; ++r) {
            int idx = base + r;
            c[r] = (idx < NN) ? cnt[idx] : 0;
        }
    }

    int loc[20];
    int s = 0;
    #pragma unroll
    for (int r = 0; r < 20; ++r) { loc[r] = s; s += c[r]; }

    const int lane = t & 63, wv = t >> 6;
    int incl = s;
    #pragma unroll
    for (int d2 = 1; d2 < 64; d2 <<= 1) {
        int u = __shfl_up(incl, d2);
        if (lane >= d2) incl += u;
    }
    if (lane == 63) wtot[wv] = incl;
    __syncthreads();
    int wbase = 0;
    for (int p2 = 0; p2 < wv; ++p2) wbase += wtot[p2];

    const int excl = wbase + incl - s;

    int o[20];
    #pragma unroll
    for (int r = 0; r < 20; ++r) o[r] = excl + loc[r];
    float iv[20];
    #pragma unroll
    for (int r = 0; r < 20; ++r) iv[r] = 1.0f / fmaxf((float)c[r], 1.0f);

    if (base + 20 <= NN) {
        #pragma unroll
        for (int q = 0; q < 5; ++q) {
            ((int4*)(off + base))[q]    = *(const int4*)&o[4 * q];
            ((int4*)(cur + base))[q]    = *(const int4*)&o[4 * q];
            ((float4*)(invc + base))[q] = *(const float4*)&iv[4 * q];
        }
    } else {
        #pragma unroll
        for (int r = 0; r < 20; ++r) {
            int idx = base + r;
            if (idx < NN) { off[idx] = o[r]; cur[idx] = o[r]; invc[idx] = iv[r]; }
        }
    }
    if (t == 0) off[NN] = EE;
}

__global__ void scatter_kernel(const int* __restrict__ ei, const float* __restrict__ ewt,
                               int* __restrict__ cur,
                               int* __restrict__ ssrc, float* __restrict__ sew) {
    int e = blockIdx.x * 256 + threadIdx.x;
    if (e < EE) {
        int d = ei[EE + e];
        int pos = atomicAdd(&cur[d], 1);
        ssrc[pos] = ei[e];
        sew[pos] = ewt[e];
    }
}

// Wt build (verified layout) + fp16 cast of x. idx<52224: weights; then x16.
__global__ void build_wt(const float* __restrict__ w2a, const float* __restrict__ b2a,
                         const float* __restrict__ ra,
                         const float* __restrict__ w2b, const float* __restrict__ b2b,
                         const float* __restrict__ rb,
                         const float* __restrict__ x,
                         _Float16* __restrict__ Wt1, _Float16* __restrict__ Wt2,
                         _Float16* __restrict__ x16) {
    int idx = blockIdx.x * 256 + threadIdx.x;
    if (idx < 17408) {                       // 32 * 544 (CIN=16)
        int o = idx / 544, k = idx % 544;
        float v;
        if (k < 512) {
            int m = k & 31, i = k >> 5;
            v = w2a[m * 512 + i * 32 + o];
        } else if (k < 528) {
            v = b2a[(k - 512) * 32 + o];
        } else {
            v = ra[(k - 528) * 32 + o];
        }
        Wt1[o * 544 + k] = (_Float16)v;
    } else if (idx < 52224) {                // + 32 * 1088 (CIN=32)
        int j = idx - 17408;
        int o = j / 1088, k = j % 1088;
        float v;
        if (k < 1024) {
            int m = k & 31, i = k >> 5;
            v = w2b[m * 1024 + i * 32 + o];
        } else if (k < 1056) {
            v = b2b[(k - 1024) * 32 + o];
        } else {
            v = rb[(k - 1056) * 32 + o];
        }
        Wt2[o * 1088 + k] = (_Float16)v;
    } else if (idx < 52224 + NN * 16) {      // x -> fp16
        int j = idx - 52224;
        x16[j] = (_Float16)x[j];
    }
}

// ---------------- fused layer: async-staged fp16 edges -> LDS -> MFMA ------
// Block = 512 thr (8 waves), 16 nodes, CSR range [E0,E1), CAP=192 staged.
// A1: stage ssrc/sew.  A2: async fp16 row gathers (2 elems/lane, RPG=128/CIN
// rows per instr).  A3: per-node accumulation; per edge 2 (CIN=32) or 1
// (CIN=16) ds_read_b128 of f16x8.  B: verified 8-way K-split MFMA + epilogue.
// Layer-1 output h1 is written fp16 (F is fp16 anyway). Overflow beyond CAP
// (P~1e-5) takes a correct global-gather slow path.

template <int CIN, bool DECODE>
__global__ __launch_bounds__(512, 6) void fused_layer(
    const _Float16* __restrict__ xin16, const int* __restrict__ ssrc,
    const float* __restrict__ sew, const int* __restrict__ off,
    const float* __restrict__ invc, const float* __restrict__ w1,
    const float* __restrict__ b1, const _Float16* __restrict__ Wt,
    const float* __restrict__ bias, void* __restrict__ outp,
    const float* __restrict__ dw, const float* __restrict__ db) {
    constexpr int K = 34 * CIN;              // 544 or 1088
    constexpr int LDK = K + 4;
    constexpr int JS = (32 * CIN) / 64;      // 8 or 16
    constexpr int NH = JS / 8;               // f16x8 reads per edge: 1 or 2
    constexpr int steps = K / 32;            // 17 or 34
    constexpr int CAP = 192;                 // staged-edge capacity
    constexpr int RPG = 128 / CIN;           // rows per staging instr: 8 or 4
    constexpr int LPR = CIN / 2;             // lanes per row

    extern __shared__ char smem[];
    _Float16* Fl = (_Float16*)smem;                          // 16*LDK f16
    float* pool = (float*)(smem + (size_t)16 * LDK * 2);
    int*   Is = (int*)pool;                                  // [CAP]
    float* Es = pool + CAP;                                  // [CAP]
    _Float16* Xs = (_Float16*)(pool + 2 * CAP);              // [CAP*CIN] f16
    float* red = pool;                                       // phase-B alias

    const int t = threadIdx.x;
    const int n0 = blockIdx.x * 16;
    const int lane = t & 63, w = t >> 6;     // 8 waves

    const int E0 = off[n0];
    const int E1 = off[n0 + 16];
    const int L = E1 - E0;
    const int Lc = (L < CAP) ? L : CAP;

    // ---- A1: stage edge indices + weights ----
    if (w == 0) {
        for (int c = 0; c < Lc; c += 64) {
            int idx = c + lane; idx = (idx < L - 1) ? idx : (L - 1);
            gload_lds_b32(ssrc + E0 + idx, Is + c);
        }
    } else if (w == 1) {
        for (int c = 0; c < Lc; c += 64) {
            int idx = c + lane; idx = (idx < L - 1) ? idx : (L - 1);
            gload_lds_b32(sew + E0 + idx, Es + c);
        }
    }
    __syncthreads();

    // ---- A2: async fp16 row gathers ----
    {
        const int G = (Lc + RPG - 1) / RPG;
        const int er = lane / LPR;            // row within group
        const int ecp = lane % LPR;           // elem pair
        for (int p = w; p < G; p += 8) {
            int el = p * RPG + er; el = (el < Lc - 1) ? el : (Lc - 1);
            int sn = Is[el];
            gload_lds_b32(xin16 + (size_t)sn * CIN + 2 * ecp,
                          Xs + (size_t)p * RPG * CIN);
        }
    }
    __syncthreads();

    // ---- A3: per-node accumulation from LDS ----
    {
        const int m = lane & 31;
        const int ihalf = (lane >> 5) * JS;
        const int i0 = lane & (CIN - 1);
        const float w1v = w1[m];
        const float b1v = b1[m];

        for (int c = 0; c < 2; ++c) {
            const int nsub = w * 2 + c;
            const int d = n0 + nsub;
            float Sacc[JS];
            #pragma unroll
            for (int j = 0; j < JS; ++j) Sacc[j] = 0.f;
            float S0 = 0.f;

            const int e0l = off[d] - E0, e1l = off[d + 1] - E0;
            const int eL = (e1l < Lc) ? e1l : Lc;
            const float iv = invc[d];

            #pragma unroll 2
            for (int el = e0l; el < eL; ++el) {
                const float ew = Es[el];
                const float hv = silu_f(fmaf(ew, w1v, b1v));
                const int rb = el * CIN;
                f16x8 xh[NH];
                #pragma unroll
                for (int q = 0; q < NH; ++q)
                    xh[q] = *(const f16x8*)&Xs[rb + ihalf + 8 * q];
                #pragma unroll
                for (int q = 0; q < NH; ++q)
                    #pragma unroll
                    for (int j = 0; j < 8; ++j)
                        Sacc[8 * q + j] = fmaf((float)xh[q][j], hv, Sacc[8 * q + j]);
                S0 += (float)Xs[rb + i0];
            }
            // cold overflow path (L > CAP only)
            for (int el = eL; el < e1l; ++el) {
                const int sn2 = ssrc[E0 + el];
                const float ew2 = sew[E0 + el];
                const float hv2 = silu_f(fmaf(ew2, w1v, b1v));
                const _Float16* xrow = xin16 + (size_t)sn2 * CIN;
                #pragma unroll
                for (int q = 0; q < NH; ++q) {
                    f16x8 xq = *(const f16x8*)(xrow + ihalf + 8 * q);
                    #pragma unroll
                    for (int j = 0; j < 8; ++j)
                        Sacc[8 * q + j] = fmaf((float)xq[j], hv2, Sacc[8 * q + j]);
                }
                S0 += (float)xrow[i0];
            }

            _Float16* Fr = Fl + (size_t)nsub * LDK;
            #pragma unroll
            for (int j = 0; j < JS; ++j)
                Fr[(ihalf + j) * 32 + m] = (_Float16)(Sacc[j] * iv);
            if (lane < CIN)
                Fr[32 * CIN + lane] = (_Float16)(S0 * iv);
            else if (lane < 2 * CIN)
                Fr[32 * CIN + lane] = xin16[(size_t)d * CIN + (lane - CIN)];
        }
    }
    __syncthreads();

    // ---- Phase B: 8-way K-split MFMA ----
    const int o16 = lane & 15, g = lane >> 4;

    const _Float16* Arow = Fl + (size_t)o16 * LDK + g * 4;
    const _Float16* B0 = Wt + (size_t)o16 * K + g * 4;
    const _Float16* B1 = Wt + (size_t)(o16 + 16) * K + g * 4;

    f32x4 acc0 = {0.f, 0.f, 0.f, 0.f};
    f32x4 acc1 = {0.f, 0.f, 0.f, 0.f};

    const int sb = (steps * w) >> 3;
    const int se = (steps * (w + 1)) >> 3;
    #pragma unroll 2
    for (int s = sb; s < se; ++s) {
        const int k0 = s * 32;
        f16x4 alo = *(const f16x4*)(Arow + k0);
        f16x4 ahi = *(const f16x4*)(Arow + k0 + 16);
        f16x4 b0l = *(const f16x4*)(B0 + k0);
        f16x4 b0h = *(const f16x4*)(B0 + k0 + 16);
        f16x4 b1l = *(const f16x4*)(B1 + k0);
        f16x4 b1h = *(const f16x4*)(B1 + k0 + 16);
        f16x8 a, bb0, bb1;
        #pragma unroll
        for (int j = 0; j < 4; ++j) {
            a[j] = alo[j];  a[j + 4] = ahi[j];
            bb0[j] = b0l[j]; bb0[j + 4] = b0h[j];
            bb1[j] = b1l[j]; bb1[j + 4] = b1h[j];
        }
        acc0 = __builtin_amdgcn_mfma_f32_16x16x32_f16(a, bb0, acc0, 0, 0, 0);
        acc1 = __builtin_amdgcn_mfma_f32_16x16x32_f16(a, bb1, acc1, 0, 0, 0);
    }

    if (w > 0) {
        float* rw = red + (w - 1) * 512;
        #pragma unroll
        for (int r = 0; r < 4; ++r) {
            rw[(g * 4 + r) * 32 + o16]      = acc0[r];
            rw[(g * 4 + r) * 32 + 16 + o16] = acc1[r];
        }
    }
    __syncthreads();
    if (w == 0) {
        #pragma unroll
        for (int r = 0; r < 4; ++r) {
            const int ro = (g * 4 + r) * 32 + o16;
            #pragma unroll
            for (int p = 0; p < 7; ++p) {
                acc0[r] += red[p * 512 + ro];
                acc1[r] += red[p * 512 + ro + 16];
            }
        }
        const float bb0 = bias[o16], bb1 = bias[o16 + 16];
        const int nrow = n0 + g * 4;
        if (!DECODE) {
            _Float16* op = (_Float16*)outp;
            #pragma unroll
            for (int r = 0; r < 4; ++r) {
                op[(size_t)(nrow + r) * 32 + o16]      = (_Float16)silu_f(acc0[r] + bb0);
                op[(size_t)(nrow + r) * 32 + 16 + o16] = (_Float16)silu_f(acc1[r] + bb1);
            }
        } else {
            float* op = (float*)outp;
            const float w0 = dw[o16], w1v = dw[o16 + 16];
            const float dbv = db[0];
            #pragma unroll
            for (int r = 0; r < 4; ++r) {
                float p = silu_f(acc0[r] + bb0) * w0 + silu_f(acc1[r] + bb1) * w1v;
                p += __shfl_xor(p, 1);
                p += __shfl_xor(p, 2);
                p += __shfl_xor(p, 4);
                p += __shfl_xor(p, 8);
                if (o16 == 0) op[nrow + r] = p + dbv;
            }
        }
    }
}

// ---------------- launch ----------------

extern "C" void kernel_launch(void* const* d_in, const int* in_sizes, int n_in,
                              void* d_out, int out_size, void* d_ws, size_t ws_size,
                              hipStream_t stream) {
    const float* x      = (const float*)d_in[0];
    const int*   ei     = (const int*)d_in[1];
    const float* ew     = (const float*)d_in[2];
    const float* en1_w1 = (const float*)d_in[3];
    const float* en1_b1 = (const float*)d_in[4];
    const float* en1_w2 = (const float*)d_in[5];
    const float* en1_b2 = (const float*)d_in[6];
    const float* root1  = (const float*)d_in[7];
    const float* bias1  = (const float*)d_in[8];
    const float* en2_w1 = (const float*)d_in[9];
    const float* en2_b1 = (const float*)d_in[10];
    const float* en2_w2 = (const float*)d_in[11];
    const float* en2_b2 = (const float*)d_in[12];
    const float* root2  = (const float*)d_in[13];
    const float* bias2  = (const float*)d_in[14];
    const float* dec_w  = (const float*)d_in[15];
    const float* dec_b  = (const float*)d_in[16];
    float* out = (float*)d_out;
    (void)in_sizes; (void)n_in; (void)out_size; (void)ws_size;

    char* wp = (char*)d_ws;
    auto alloc = [&](size_t bytes) {
        char* p = wp;
        wp += (bytes + 255) & ~(size_t)255;
        return p;
    };
    int*      cnt  = (int*)alloc((size_t)NN * 4);
    int*      off  = (int*)alloc((size_t)(NN + 1) * 4);
    int*      cur  = (int*)alloc((size_t)NN * 4);
    float*    invc = (float*)alloc((size_t)NN * 4);
    int*      ssrc = (int*)alloc((size_t)EE * 4);
    float*    sew  = (float*)alloc((size_t)EE * 4);
    _Float16* h1h  = (_Float16*)alloc((size_t)NN * 32 * 2);
    _Float16* x16  = (_Float16*)alloc((size_t)NN * 16 * 2);
    _Float16* Wt1  = (_Float16*)alloc((size_t)17408 * 2);
    _Float16* Wt2  = (_Float16*)alloc((size_t)34816 * 2);

    hipMemsetAsync(cnt, 0, (size_t)NN * 4, stream);

    count_kernel<<<(EE + 255) / 256, 256, 0, stream>>>(ei, cnt);
    scan_kernel<<<1, 1024, 0, stream>>>(cnt, off, cur, invc);
    scatter_kernel<<<(EE + 255) / 256, 256, 0, stream>>>(ei, ew, cur, ssrc, sew);
    build_wt<<<(52224 + NN * 16 + 255) / 256, 256, 0, stream>>>(
        en1_w2, en1_b2, root1, en2_w2, en2_b2, root2, x, Wt1, Wt2, x16);

    auto f1 = fused_layer<16, false>;
    auto f2 = fused_layer<32, true>;
    (void)hipFuncSetAttribute((const void*)f1,
                              hipFuncAttributeMaxDynamicSharedMemorySize, 163840);
    (void)hipFuncSetAttribute((const void*)f2,
                              hipFuncAttributeMaxDynamicSharedMemorySize, 163840);

    // lds = Fl + pool;  pool = max(7*512*4, 2*CAP*4 + CAP*CIN*2) = 14336 B
    const size_t lds1 = (size_t)16 * (34 * 16 + 4) * 2 + 14336;  // 31,872 B
    const size_t lds2 = (size_t)16 * (34 * 32 + 4) * 2 + 14336;  // 49,280 B

    fused_layer<16, false><<<NN / 16, 512, lds1, stream>>>(
        x16, ssrc, sew, off, invc, en1_w1, en1_b1, Wt1, bias1, h1h, nullptr, nullptr);
    fused_layer<32, true><<<NN / 16, 512, lds2, stream>>>(
        h1h, ssrc, sew, off, invc, en2_w1, en2_b1, Wt2, bias2, out, dec_w, dec_b);
}

// Round 12
// 99.574 us; speedup vs baseline: 1.0375x; 1.0375x over previous
//
#include <hip/hip_runtime.h>
#include <hip/hip_bf16.h>

#define NN 20000
#define EE 160000
#define HH 32
#define MIDD 32

typedef _Float16 f16x4 __attribute__((ext_vector_type(4)));
typedef _Float16 f16x8 __attribute__((ext_vector_type(8)));
typedef float f32x4 __attribute__((ext_vector_type(4)));

__device__ __forceinline__ float silu_f(float v) {
    return __fdividef(v, 1.0f + __expf(-v));
}

// async global->LDS, 4B per lane; LDS dest = wave-uniform base + 4*lane.
__device__ __forceinline__ void gload_lds_b32(const void* gsrc, void* ldst) {
    __builtin_amdgcn_global_load_lds(
        (const __attribute__((address_space(1))) void*)gsrc,
        (__attribute__((address_space(3))) void*)ldst, 4, 0, 0);
}

// ---------------- prep kernels ----------------

__global__ void count_kernel(const int* __restrict__ ei, int* __restrict__ cnt) {
    int e = blockIdx.x * 256 + threadIdx.x;
    if (e < EE) atomicAdd(&cnt[ei[EE + e]], 1);
}

// Vectorized single-block scan (round-10 verified).
__global__ __launch_bounds__(1024) void scan_kernel(
    const int* __restrict__ cnt, int* __restrict__ off,
    int* __restrict__ cur, float* __restrict__ invc) {
    const int t = threadIdx.x;
    const int base = t * 20;
    __shared__ int wtot[16];

    int c[20];
    if (base + 20 <= NN) {
        const int4* p = (const int4*)(cnt + base);
        #pragma unroll
        for (int q = 0; q < 5; ++q) *(int4*)&c[4 * q] = p[q];
    } else {
        #pragma unroll
        for (int r = 0; r < 20; ++r) {
            int idx = base + r;
            c[r] = (idx < NN) ? cnt[idx] : 0;
        }
    }

    int loc[20];
    int s = 0;
    #pragma unroll
    for (int r = 0; r < 20; ++r) { loc[r] = s; s += c[r]; }

    const int lane = t & 63, wv = t >> 6;
    int incl = s;
    #pragma unroll
    for (int d2 = 1; d2 < 64; d2 <<= 1) {
        int u = __shfl_up(incl, d2);
        if (lane >= d2) incl += u;
    }
    if (lane == 63) wtot[wv] = incl;
    __syncthreads();
    int wbase = 0;
    for (int p2 = 0; p2 < wv; ++p2) wbase += wtot[p2];

    const int excl = wbase + incl - s;

    int o[20];
    #pragma unroll
    for (int r = 0; r < 20; ++r) o[r] = excl + loc[r];
    float iv[20];
    #pragma unroll
    for (int r = 0; r < 20; ++r) iv[r] = 1.0f / fmaxf((float)c[r], 1.0f);

    if (base + 20 <= NN) {
        #pragma unroll
        for (int q = 0; q < 5; ++q) {
            ((int4*)(off + base))[q]    = *(const int4*)&o[4 * q];
            ((int4*)(cur + base))[q]    = *(const int4*)&o[4 * q];
            ((float4*)(invc + base))[q] = *(const float4*)&iv[4 * q];
        }
    } else {
        #pragma unroll
        for (int r = 0; r < 20; ++r) {
            int idx = base + r;
            if (idx < NN) { off[idx] = o[r]; cur[idx] = o[r]; invc[idx] = iv[r]; }
        }
    }
    if (t == 0) off[NN] = EE;
}

// scatter (src, ew-bits) as one int2 per edge -> halves random store line touches.
__global__ void scatter_kernel(const int* __restrict__ ei, const float* __restrict__ ewt,
                               int* __restrict__ cur, int2* __restrict__ spair) {
    int e = blockIdx.x * 256 + threadIdx.x;
    if (e < EE) {
        int d = ei[EE + e];
        int pos = atomicAdd(&cur[d], 1);
        spair[pos] = make_int2(ei[e], __float_as_int(ewt[e]));
    }
}

// Wt build (verified layout) + fp16 cast of x.
__global__ void build_wt(const float* __restrict__ w2a, const float* __restrict__ b2a,
                         const float* __restrict__ ra,
                         const float* __restrict__ w2b, const float* __restrict__ b2b,
                         const float* __restrict__ rb,
                         const float* __restrict__ x,
                         _Float16* __restrict__ Wt1, _Float16* __restrict__ Wt2,
                         _Float16* __restrict__ x16) {
    int idx = blockIdx.x * 256 + threadIdx.x;
    if (idx < 17408) {                       // 32 * 544 (CIN=16)
        int o = idx / 544, k = idx % 544;
        float v;
        if (k < 512) {
            int m = k & 31, i = k >> 5;
            v = w2a[m * 512 + i * 32 + o];
        } else if (k < 528) {
            v = b2a[(k - 512) * 32 + o];
        } else {
            v = ra[(k - 528) * 32 + o];
        }
        Wt1[o * 544 + k] = (_Float16)v;
    } else if (idx < 52224) {                // + 32 * 1088 (CIN=32)
        int j = idx - 17408;
        int o = j / 1088, k = j % 1088;
        float v;
        if (k < 1024) {
            int m = k & 31, i = k >> 5;
            v = w2b[m * 1024 + i * 32 + o];
        } else if (k < 1056) {
            v = b2b[(k - 1024) * 32 + o];
        } else {
            v = rb[(k - 1056) * 32 + o];
        }
        Wt2[o * 1088 + k] = (_Float16)v;
    } else if (idx < 52224 + NN * 16) {      // x -> fp16
        int j = idx - 52224;
        x16[j] = (_Float16)x[j];
    }
}

// ---------------- fused layer: MFMA-everything --------------------------
// Block = 512 thr (8 waves), 16 nodes, CSR range [E0,E1), chunked by CAP=192.
// Per chunk: A1 stage (src,ew) pairs -> LDS; A2 async fp16 x-row gathers +
// H build (h[e][m] = silu(ew*w1[m]+b1[m]), all 512 threads); A3 per-node
// aggregation VIA MFMA: S(32 x CIN) = H^T(32 x deg) X(deg x CIN) using
// 16x16x32 frags (A = H masked to the node's slot range, B = X rows; extra
// ones-row A gives S0). Accs persist across chunks -> no overflow path.
// Tail: write S*inv, S0*inv, x_d into Fl. Phase B: verified 8-way K-split
// MFMA F @ Wt + bias/silu (+decode) epilogue; red[] aliases the pool.

template <int CIN, bool DECODE>
__global__ __launch_bounds__(512, 4) void fused_layer(
    const _Float16* __restrict__ xin16, const int* __restrict__ spair,
    const int* __restrict__ off, const float* __restrict__ invc,
    const float* __restrict__ w1, const float* __restrict__ b1,
    const _Float16* __restrict__ Wt, const float* __restrict__ bias,
    void* __restrict__ outp, const float* __restrict__ dw,
    const float* __restrict__ db) {
    constexpr int K = 34 * CIN;              // 544 or 1088
    constexpr int LDK = K + 4;
    constexpr int steps = K / 32;            // 17 or 34
    constexpr int CAP = 192;                 // staged edges per chunk
    constexpr int RPG = 128 / CIN;           // rows per gather instr: 8 or 4
    constexpr int LPR = CIN / 2;             // lanes per row
    constexpr int NIH = CIN / 16;            // i-halves: 1 or 2

    extern __shared__ char smem[];
    _Float16* Fl = (_Float16*)smem;                       // 16*LDK f16
    char* poolb = smem + (size_t)16 * LDK * 2;
    int* Ps = (int*)poolb;                                // [2*CAP+64] pairs
    _Float16* Xs = (_Float16*)(poolb + (2 * CAP + 64) * 4); // [CAP*CIN]
    _Float16* Hs = Xs + CAP * CIN;                        // [CAP*32]
    float* red = (float*)poolb;                           // phase-B alias

    const int t = threadIdx.x;
    const int n0 = blockIdx.x * 16;
    const int lane = t & 63, w = t >> 6;     // 8 waves
    const int col = lane & 15, g4 = (lane >> 4) * 4;

    const int E0 = off[n0], E1 = off[n0 + 16];
    const int L = E1 - E0;

    // node ranges for this wave's two nodes (block-local edge indices)
    const int d0 = n0 + w * 2;
    const int e0l0 = off[d0] - E0;
    const int e1l0 = off[d0 + 1] - E0;
    const int e1l1 = off[d0 + 2] - E0;       // node1 = [e1l0, e1l1)

    f32x4 aS[2][2][NIH];                     // [node][m-half][i-half]
    f32x4 a0[2][NIH];                        // ones-row (S0)
    #pragma unroll
    for (int c = 0; c < 2; ++c) {
        #pragma unroll
        for (int mh = 0; mh < 2; ++mh)
            #pragma unroll
            for (int ih = 0; ih < NIH; ++ih) aS[c][mh][ih] = (f32x4){0.f, 0.f, 0.f, 0.f};
        #pragma unroll
        for (int ih = 0; ih < NIH; ++ih) a0[c][ih] = (f32x4){0.f, 0.f, 0.f, 0.f};
    }

    for (int base = 0; base < L; base += CAP) {
        const int Lc = (L - base < CAP) ? (L - base) : CAP;

        // ---- A1: stage (src, ew) pairs ----
        for (int c = w * 64; c < 2 * Lc; c += 512) {
            int gidx = 2 * (E0 + base) + c + lane;
            gidx = (gidx < 2 * EE) ? gidx : (2 * EE - 1);
            gload_lds_b32(spair + gidx, Ps + c);
        }
        __syncthreads();

        // ---- A2: async fp16 x-row gathers ----
        {
            const int G = (Lc + RPG - 1) / RPG;
            const int er = lane / LPR, ecp = lane % LPR;
            for (int p = w; p < G; p += 8) {
                int el = p * RPG + er; el = (el < Lc - 1) ? el : (Lc - 1);
                int sn = Ps[2 * el];
                gload_lds_b32(xin16 + (size_t)sn * CIN + 2 * ecp,
                              Xs + (size_t)p * RPG * CIN);
            }
        }
        // ---- H build (overlaps gather latency) ----
        for (int idx = t; idx < Lc * 32; idx += 512) {
            int e = idx >> 5, m = idx & 31;
            float ew = __int_as_float(Ps[2 * e + 1]);
            Hs[idx] = (_Float16)silu_f(fmaf(ew, w1[m], b1[m]));
        }
        __syncthreads();

        // ---- A3: per-node MFMA aggregation ----
        #pragma unroll
        for (int c = 0; c < 2; ++c) {
            int lo = ((c == 0) ? e0l0 : e1l0) - base;
            int hi = ((c == 0) ? e1l0 : e1l1) - base;
            lo = (lo < 0) ? 0 : lo;
            hi = (hi > Lc) ? Lc : hi;
            for (int ks = lo; ks < hi; ks += 32) {
                f16x8 bf[NIH];
                #pragma unroll
                for (int ih = 0; ih < NIH; ++ih)
                    #pragma unroll
                    for (int j = 0; j < 4; ++j) {
                        int k1 = ks + g4 + j, k2 = k1 + 16;
                        int c1 = (k1 < hi) ? k1 : (Lc - 1);
                        int c2 = (k2 < hi) ? k2 : (Lc - 1);
                        bf[ih][j]     = Xs[c1 * CIN + ih * 16 + col];
                        bf[ih][j + 4] = Xs[c2 * CIN + ih * 16 + col];
                    }
                f16x8 af[2];
                #pragma unroll
                for (int mh = 0; mh < 2; ++mh)
                    #pragma unroll
                    for (int j = 0; j < 4; ++j) {
                        int k1 = ks + g4 + j, k2 = k1 + 16;
                        _Float16 v1 = Hs[((k1 < hi) ? k1 : (Lc - 1)) * 32 + mh * 16 + col];
                        _Float16 v2 = Hs[((k2 < hi) ? k2 : (Lc - 1)) * 32 + mh * 16 + col];
                        af[mh][j]     = (k1 < hi) ? v1 : (_Float16)0;
                        af[mh][j + 4] = (k2 < hi) ? v2 : (_Float16)0;
                    }
                f16x8 ao;
                #pragma unroll
                for (int j = 0; j < 4; ++j) {
                    int k1 = ks + g4 + j, k2 = k1 + 16;
                    ao[j]     = (col == 0 && k1 < hi) ? (_Float16)1 : (_Float16)0;
                    ao[j + 4] = (col == 0 && k2 < hi) ? (_Float16)1 : (_Float16)0;
                }
                #pragma unroll
                for (int mh = 0; mh < 2; ++mh)
                    #pragma unroll
                    for (int ih = 0; ih < NIH; ++ih)
                        aS[c][mh][ih] = __builtin_amdgcn_mfma_f32_16x16x32_f16(
                            af[mh], bf[ih], aS[c][mh][ih], 0, 0, 0);
                #pragma unroll
                for (int ih = 0; ih < NIH; ++ih)
                    a0[c][ih] = __builtin_amdgcn_mfma_f32_16x16x32_f16(
                        ao, bf[ih], a0[c][ih], 0, 0, 0);
            }
        }
        if (base + CAP < L) __syncthreads();   // before re-staging (uniform)
    }

    // ---- tail: write F rows ----
    #pragma unroll
    for (int c = 0; c < 2; ++c) {
        const int d = n0 + w * 2 + c;
        const float iv = invc[d];
        _Float16* Fr = Fl + (size_t)(w * 2 + c) * LDK;
        #pragma unroll
        for (int mh = 0; mh < 2; ++mh)
            #pragma unroll
            for (int ih = 0; ih < NIH; ++ih)
                #pragma unroll
                for (int r = 0; r < 4; ++r)
                    Fr[32 * (ih * 16 + col) + mh * 16 + g4 + r] =
                        (_Float16)(aS[c][mh][ih][r] * iv);
        if (g4 == 0) {                       // row 0 of ones-tile = S0
            #pragma unroll
            for (int ih = 0; ih < NIH; ++ih)
                Fr[32 * CIN + ih * 16 + col] = (_Float16)(a0[c][ih][0] * iv);
        }
        if (lane >= CIN && lane < 2 * CIN)
            Fr[32 * CIN + lane] = xin16[(size_t)d * CIN + (lane - CIN)];
    }
    __syncthreads();

    // ---- Phase B: 8-way K-split MFMA (verified) ----
    const int o16 = col, g = lane >> 4;

    const _Float16* Arow = Fl + (size_t)o16 * LDK + g * 4;
    const _Float16* B0 = Wt + (size_t)o16 * K + g * 4;
    const _Float16* B1 = Wt + (size_t)(o16 + 16) * K + g * 4;

    f32x4 acc0 = {0.f, 0.f, 0.f, 0.f};
    f32x4 acc1 = {0.f, 0.f, 0.f, 0.f};

    const int sb = (steps * w) >> 3;
    const int se = (steps * (w + 1)) >> 3;
    #pragma unroll 2
    for (int s = sb; s < se; ++s) {
        const int k0 = s * 32;
        f16x4 alo = *(const f16x4*)(Arow + k0);
        f16x4 ahi = *(const f16x4*)(Arow + k0 + 16);
        f16x4 b0l = *(const f16x4*)(B0 + k0);
        f16x4 b0h = *(const f16x4*)(B0 + k0 + 16);
        f16x4 b1l = *(const f16x4*)(B1 + k0);
        f16x4 b1h = *(const f16x4*)(B1 + k0 + 16);
        f16x8 a, bb0, bb1;
        #pragma unroll
        for (int j = 0; j < 4; ++j) {
            a[j] = alo[j];  a[j + 4] = ahi[j];
            bb0[j] = b0l[j]; bb0[j + 4] = b0h[j];
            bb1[j] = b1l[j]; bb1[j + 4] = b1h[j];
        }
        acc0 = __builtin_amdgcn_mfma_f32_16x16x32_f16(a, bb0, acc0, 0, 0, 0);
        acc1 = __builtin_amdgcn_mfma_f32_16x16x32_f16(a, bb1, acc1, 0, 0, 0);
    }

    if (w > 0) {
        float* rw = red + (w - 1) * 512;
        #pragma unroll
        for (int r = 0; r < 4; ++r) {
            rw[(g * 4 + r) * 32 + o16]      = acc0[r];
            rw[(g * 4 + r) * 32 + 16 + o16] = acc1[r];
        }
    }
    __syncthreads();
    if (w == 0) {
        #pragma unroll
        for (int r = 0; r < 4; ++r) {
            const int ro = (g * 4 + r) * 32 + o16;
            #pragma unroll
            for (int p = 0; p < 7; ++p) {
                acc0[r] += red[p * 512 + ro];
                acc1[r] += red[p * 512 + ro + 16];
            }
        }
        const float bb0 = bias[o16], bb1 = bias[o16 + 16];
        const int nrow = n0 + g * 4;
        if (!DECODE) {
            _Float16* op = (_Float16*)outp;
            #pragma unroll
            for (int r = 0; r < 4; ++r) {
                op[(size_t)(nrow + r) * 32 + o16]      = (_Float16)silu_f(acc0[r] + bb0);
                op[(size_t)(nrow + r) * 32 + 16 + o16] = (_Float16)silu_f(acc1[r] + bb1);
            }
        } else {
            float* op = (float*)outp;
            const float w0 = dw[o16], w1v = dw[o16 + 16];
            const float dbv = db[0];
            #pragma unroll
            for (int r = 0; r < 4; ++r) {
                float p = silu_f(acc0[r] + bb0) * w0 + silu_f(acc1[r] + bb1) * w1v;
                p += __shfl_xor(p, 1);
                p += __shfl_xor(p, 2);
                p += __shfl_xor(p, 4);
                p += __shfl_xor(p, 8);
                if (o16 == 0) op[nrow + r] = p + dbv;
            }
        }
    }
}

// ---------------- launch ----------------

extern "C" void kernel_launch(void* const* d_in, const int* in_sizes, int n_in,
                              void* d_out, int out_size, void* d_ws, size_t ws_size,
                              hipStream_t stream) {
    const float* x      = (const float*)d_in[0];
    const int*   ei     = (const int*)d_in[1];
    const float* ew     = (const float*)d_in[2];
    const float* en1_w1 = (const float*)d_in[3];
    const float* en1_b1 = (const float*)d_in[4];
    const float* en1_w2 = (const float*)d_in[5];
    const float* en1_b2 = (const float*)d_in[6];
    const float* root1  = (const float*)d_in[7];
    const float* bias1  = (const float*)d_in[8];
    const float* en2_w1 = (const float*)d_in[9];
    const float* en2_b1 = (const float*)d_in[10];
    const float* en2_w2 = (const float*)d_in[11];
    const float* en2_b2 = (const float*)d_in[12];
    const float* root2  = (const float*)d_in[13];
    const float* bias2  = (const float*)d_in[14];
    const float* dec_w  = (const float*)d_in[15];
    const float* dec_b  = (const float*)d_in[16];
    float* out = (float*)d_out;
    (void)in_sizes; (void)n_in; (void)out_size; (void)ws_size;

    char* wp = (char*)d_ws;
    auto alloc = [&](size_t bytes) {
        char* p = wp;
        wp += (bytes + 255) & ~(size_t)255;
        return p;
    };
    int*      cnt   = (int*)alloc((size_t)NN * 4);
    int*      off   = (int*)alloc((size_t)(NN + 1) * 4);
    int*      cur   = (int*)alloc((size_t)NN * 4);
    float*    invc  = (float*)alloc((size_t)NN * 4);
    int2*     spair = (int2*)alloc((size_t)EE * 8);
    _Float16* h1h   = (_Float16*)alloc((size_t)NN * 32 * 2);
    _Float16* x16   = (_Float16*)alloc((size_t)NN * 16 * 2);
    _Float16* Wt1   = (_Float16*)alloc((size_t)17408 * 2);
    _Float16* Wt2   = (_Float16*)alloc((size_t)34816 * 2);

    hipMemsetAsync(cnt, 0, (size_t)NN * 4, stream);

    count_kernel<<<(EE + 255) / 256, 256, 0, stream>>>(ei, cnt);
    scan_kernel<<<1, 1024, 0, stream>>>(cnt, off, cur, invc);
    scatter_kernel<<<(EE + 255) / 256, 256, 0, stream>>>(ei, ew, cur, spair);
    build_wt<<<(52224 + NN * 16 + 255) / 256, 256, 0, stream>>>(
        en1_w2, en1_b2, root1, en2_w2, en2_b2, root2, x, Wt1, Wt2, x16);

    auto f1 = fused_layer<16, false>;
    auto f2 = fused_layer<32, true>;
    (void)hipFuncSetAttribute((const void*)f1,
                              hipFuncAttributeMaxDynamicSharedMemorySize, 163840);
    (void)hipFuncSetAttribute((const void*)f2,
                              hipFuncAttributeMaxDynamicSharedMemorySize, 163840);

    // pool = (2*CAP+64)*4 + CAP*CIN*2 + CAP*64 bytes; Fl = 16*LDK*2
    const size_t lds1 = (size_t)16 * (34 * 16 + 4) * 2 + (448 * 4 + 192 * 16 * 2 + 192 * 64); // 37,760
    const size_t lds2 = (size_t)16 * (34 * 32 + 4) * 2 + (448 * 4 + 192 * 32 * 2 + 192 * 64); // 61,312

    fused_layer<16, false><<<NN / 16, 512, lds1, stream>>>(
        x16, (const int*)spair, off, invc, en1_w1, en1_b1, Wt1, bias1, h1h,
        nullptr, nullptr);
    fused_layer<32, true><<<NN / 16, 512, lds2, stream>>>(
        h1h, (const int*)spair, off, invc, en2_w1, en2_b1, Wt2, bias2, out,
        dec_w, dec_b);
}

// Round 13
// 97.233 us; speedup vs baseline: 1.0624x; 1.0241x over previous
//
#include <hip/hip_runtime.h>
#include <hip/hip_bf16.h>

#define NN 20000
#define EE 160000
#define HH 32
#define MIDD 32
#define NB 128
#define EPB 1250   // EE / NB exactly

typedef _Float16 f16x4 __attribute__((ext_vector_type(4)));
typedef _Float16 f16x8 __attribute__((ext_vector_type(8)));
typedef float f32x4 __attribute__((ext_vector_type(4)));

__device__ __forceinline__ float silu_f(float v) {
    return __fdividef(v, 1.0f + __expf(-v));
}

// async global->LDS, 4B per lane; LDS dest = wave-uniform base + 4*lane.
__device__ __forceinline__ void gload_lds_b32(const void* gsrc, void* ldst) {
    __builtin_amdgcn_global_load_lds(
        (const __attribute__((address_space(1))) void*)gsrc,
        (__attribute__((address_space(3))) void*)ldst, 4, 0, 0);
}

// ---------------- prep: per-block LDS histogram + Wt build + x16 cast ------
// blocks [0,NB): histogram of dst over this block's 1250-edge chunk
//   (u16 pairs packed in u32 LDS, 40KB), written coalesced to histG[b][n].
// blocks [NB, NB+1454): build_wt + x16 (verified round-11/12 layout).
__global__ __launch_bounds__(256) void prep_kernel(
    const int* __restrict__ ei,
    const float* __restrict__ w2a, const float* __restrict__ b2a,
    const float* __restrict__ ra,
    const float* __restrict__ w2b, const float* __restrict__ b2b,
    const float* __restrict__ rb,
    const float* __restrict__ x,
    unsigned int* __restrict__ histG,
    _Float16* __restrict__ Wt1, _Float16* __restrict__ Wt2,
    _Float16* __restrict__ x16) {
    const int t = threadIdx.x;
    if (blockIdx.x < NB) {
        __shared__ unsigned int h2[NN / 2];
        for (int i = t; i < NN / 2; i += 256) h2[i] = 0u;
        __syncthreads();
        const int base = blockIdx.x * EPB;
        for (int e = base + t; e < base + EPB; e += 256) {
            int d = ei[EE + e];
            atomicAdd(&h2[d >> 1], 1u << ((d & 1) * 16));
        }
        __syncthreads();
        unsigned int* outp = histG + (size_t)blockIdx.x * NN;
        for (int n = t; n < NN; n += 256)
            outp[n] = (h2[n >> 1] >> ((n & 1) * 16)) & 0xFFFFu;
        return;
    }
    int idx = (blockIdx.x - NB) * 256 + t;
    if (idx < 17408) {                       // 32 * 544 (CIN=16)
        int o = idx / 544, k = idx % 544;
        float v;
        if (k < 512) {
            int m = k & 31, i = k >> 5;
            v = w2a[m * 512 + i * 32 + o];
        } else if (k < 528) {
            v = b2a[(k - 512) * 32 + o];
        } else {
            v = ra[(k - 528) * 32 + o];
        }
        Wt1[o * 544 + k] = (_Float16)v;
    } else if (idx < 52224) {                // + 32 * 1088 (CIN=32)
        int j = idx - 17408;
        int o = j / 1088, k = j % 1088;
        float v;
        if (k < 1024) {
            int m = k & 31, i = k >> 5;
            v = w2b[m * 1024 + i * 32 + o];
        } else if (k < 1056) {
            v = b2b[(k - 1024) * 32 + o];
        } else {
            v = rb[(k - 1056) * 32 + o];
        }
        Wt2[o * 1088 + k] = (_Float16)v;
    } else if (idx < 52224 + NN * 16) {      // x -> fp16
        int j = idx - 52224;
        x16[j] = (_Float16)x[j];
    }
}

// per-node prefix over block histograms: histG[b][n] -> exclusive base;
// emits node totals (cnt) + invc. Coalesced per-b rows.
__global__ __launch_bounds__(256) void colscan_kernel(
    unsigned int* __restrict__ histG, int* __restrict__ cnt,
    float* __restrict__ invc) {
    const int n = blockIdx.x * 256 + threadIdx.x;
    if (n >= NN) return;
    unsigned int s = 0;
    #pragma unroll 4
    for (int b = 0; b < NB; ++b) {
        unsigned int v = histG[(size_t)b * NN + n];
        histG[(size_t)b * NN + n] = s;
        s += v;
    }
    cnt[n] = (int)s;
    invc[n] = 1.0f / fmaxf((float)s, 1.0f);
}

// Vectorized single-block scan (round-10 verified; off only).
__global__ __launch_bounds__(1024) void scan_kernel(
    const int* __restrict__ cnt, int* __restrict__ off) {
    const int t = threadIdx.x;
    const int base = t * 20;
    __shared__ int wtot[16];

    int c[20];
    if (base + 20 <= NN) {
        const int4* p = (const int4*)(cnt + base);
        #pragma unroll
        for (int q = 0; q < 5; ++q) *(int4*)&c[4 * q] = p[q];
    } else {
        #pragma unroll
        for (int r = 0; r < 20; ++r) {
            int idx = base + r;
            c[r] = (idx < NN) ? cnt[idx] : 0;
        }
    }

    int loc[20];
    int s = 0;
    #pragma unroll
    for (int r = 0; r < 20; ++r) { loc[r] = s; s += c[r]; }

    const int lane = t & 63, wv = t >> 6;
    int incl = s;
    #pragma unroll
    for (int d2 = 1; d2 < 64; d2 <<= 1) {
        int u = __shfl_up(incl, d2);
        if (lane >= d2) incl += u;
    }
    if (lane == 63) wtot[wv] = incl;
    __syncthreads();
    int wbase = 0;
    for (int p2 = 0; p2 < wv; ++p2) wbase += wtot[p2];

    const int excl = wbase + incl - s;

    int o[20];
    #pragma unroll
    for (int r = 0; r < 20; ++r) o[r] = excl + loc[r];

    if (base + 20 <= NN) {
        #pragma unroll
        for (int q = 0; q < 5; ++q)
            ((int4*)(off + base))[q] = *(const int4*)&o[4 * q];
    } else {
        #pragma unroll
        for (int r = 0; r < 20; ++r) {
            int idx = base + r;
            if (idx < NN) off[idx] = o[r];
        }
    }
    if (t == 0) off[NN] = EE;
}

// scatter without global atomics: block b replays its chunk, rank via LDS
// atomics (u16-packed), pos = off[d] + histG[b][d] + rank.
__global__ __launch_bounds__(256) void scatter2_kernel(
    const int* __restrict__ ei, const float* __restrict__ ewt,
    const int* __restrict__ off, const unsigned int* __restrict__ histG,
    int2* __restrict__ spair) {
    __shared__ unsigned int r2[NN / 2];
    const int t = threadIdx.x, b = blockIdx.x;
    for (int i = t; i < NN / 2; i += 256) r2[i] = 0u;
    __syncthreads();
    const int base = b * EPB;
    const unsigned int* hb = histG + (size_t)b * NN;
    for (int e = base + t; e < base + EPB; e += 256) {
        int d = ei[EE + e];
        unsigned int old = atomicAdd(&r2[d >> 1], 1u << ((d & 1) * 16));
        int rank = (int)((old >> ((d & 1) * 16)) & 0xFFFFu);
        int pos = off[d] + (int)hb[d] + rank;
        spair[pos] = make_int2(ei[e], __float_as_int(ewt[e]));
    }
}

// ---------------- fused layer: MFMA-everything (round-12 verified) ---------

template <int CIN, bool DECODE>
__global__ __launch_bounds__(512, 4) void fused_layer(
    const _Float16* __restrict__ xin16, const int* __restrict__ spair,
    const int* __restrict__ off, const float* __restrict__ invc,
    const float* __restrict__ w1, const float* __restrict__ b1,
    const _Float16* __restrict__ Wt, const float* __restrict__ bias,
    void* __restrict__ outp, const float* __restrict__ dw,
    const float* __restrict__ db) {
    constexpr int K = 34 * CIN;              // 544 or 1088
    constexpr int LDK = K + 4;
    constexpr int steps = K / 32;            // 17 or 34
    constexpr int CAP = 192;                 // staged edges per chunk
    constexpr int RPG = 128 / CIN;           // rows per gather instr: 8 or 4
    constexpr int LPR = CIN / 2;             // lanes per row
    constexpr int NIH = CIN / 16;            // i-halves: 1 or 2

    extern __shared__ char smem[];
    _Float16* Fl = (_Float16*)smem;                       // 16*LDK f16
    char* poolb = smem + (size_t)16 * LDK * 2;
    int* Ps = (int*)poolb;                                // [2*CAP+64] pairs
    _Float16* Xs = (_Float16*)(poolb + (2 * CAP + 64) * 4); // [CAP*CIN]
    _Float16* Hs = Xs + CAP * CIN;                        // [CAP*32]
    float* red = (float*)poolb;                           // phase-B alias

    const int t = threadIdx.x;
    const int n0 = blockIdx.x * 16;
    const int lane = t & 63, w = t >> 6;     // 8 waves
    const int col = lane & 15, g4 = (lane >> 4) * 4;

    const int E0 = off[n0], E1 = off[n0 + 16];
    const int L = E1 - E0;

    const int d0 = n0 + w * 2;
    const int e0l0 = off[d0] - E0;
    const int e1l0 = off[d0 + 1] - E0;
    const int e1l1 = off[d0 + 2] - E0;

    f32x4 aS[2][2][NIH];
    f32x4 a0[2][NIH];
    #pragma unroll
    for (int c = 0; c < 2; ++c) {
        #pragma unroll
        for (int mh = 0; mh < 2; ++mh)
            #pragma unroll
            for (int ih = 0; ih < NIH; ++ih) aS[c][mh][ih] = (f32x4){0.f, 0.f, 0.f, 0.f};
        #pragma unroll
        for (int ih = 0; ih < NIH; ++ih) a0[c][ih] = (f32x4){0.f, 0.f, 0.f, 0.f};
    }

    for (int base = 0; base < L; base += CAP) {
        const int Lc = (L - base < CAP) ? (L - base) : CAP;

        // ---- A1: stage (src, ew) pairs ----
        for (int c = w * 64; c < 2 * Lc; c += 512) {
            int gidx = 2 * (E0 + base) + c + lane;
            gidx = (gidx < 2 * EE) ? gidx : (2 * EE - 1);
            gload_lds_b32(spair + gidx, Ps + c);
        }
        __syncthreads();

        // ---- A2: async fp16 x-row gathers ----
        {
            const int G = (Lc + RPG - 1) / RPG;
            const int er = lane / LPR, ecp = lane % LPR;
            for (int p = w; p < G; p += 8) {
                int el = p * RPG + er; el = (el < Lc - 1) ? el : (Lc - 1);
                int sn = Ps[2 * el];
                gload_lds_b32(xin16 + (size_t)sn * CIN + 2 * ecp,
                              Xs + (size_t)p * RPG * CIN);
            }
        }
        // ---- H build (overlaps gather latency) ----
        for (int idx = t; idx < Lc * 32; idx += 512) {
            int e = idx >> 5, m = idx & 31;
            float ew = __int_as_float(Ps[2 * e + 1]);
            Hs[idx] = (_Float16)silu_f(fmaf(ew, w1[m], b1[m]));
        }
        __syncthreads();

        // ---- A3: per-node MFMA aggregation ----
        #pragma unroll
        for (int c = 0; c < 2; ++c) {
            int lo = ((c == 0) ? e0l0 : e1l0) - base;
            int hi = ((c == 0) ? e1l0 : e1l1) - base;
            lo = (lo < 0) ? 0 : lo;
            hi = (hi > Lc) ? Lc : hi;
            for (int ks = lo; ks < hi; ks += 32) {
                f16x8 bf[NIH];
                #pragma unroll
                for (int ih = 0; ih < NIH; ++ih)
                    #pragma unroll
                    for (int j = 0; j < 4; ++j) {
                        int k1 = ks + g4 + j, k2 = k1 + 16;
                        int c1 = (k1 < hi) ? k1 : (Lc - 1);
                        int c2 = (k2 < hi) ? k2 : (Lc - 1);
                        bf[ih][j]     = Xs[c1 * CIN + ih * 16 + col];
                        bf[ih][j + 4] = Xs[c2 * CIN + ih * 16 + col];
                    }
                f16x8 af[2];
                #pragma unroll
                for (int mh = 0; mh < 2; ++mh)
                    #pragma unroll
                    for (int j = 0; j < 4; ++j) {
                        int k1 = ks + g4 + j, k2 = k1 + 16;
                        _Float16 v1 = Hs[((k1 < hi) ? k1 : (Lc - 1)) * 32 + mh * 16 + col];
                        _Float16 v2 = Hs[((k2 < hi) ? k2 : (Lc - 1)) * 32 + mh * 16 + col];
                        af[mh][j]     = (k1 < hi) ? v1 : (_Float16)0;
                        af[mh][j + 4] = (k2 < hi) ? v2 : (_Float16)0;
                    }
                f16x8 ao;
                #pragma unroll
                for (int j = 0; j < 4; ++j) {
                    int k1 = ks + g4 + j, k2 = k1 + 16;
                    ao[j]     = (col == 0 && k1 < hi) ? (_Float16)1 : (_Float16)0;
                    ao[j + 4] = (col == 0 && k2 < hi) ? (_Float16)1 : (_Float16)0;
                }
                #pragma unroll
                for (int mh = 0; mh < 2; ++mh)
                    #pragma unroll
                    for (int ih = 0; ih < NIH; ++ih)
                        aS[c][mh][ih] = __builtin_amdgcn_mfma_f32_16x16x32_f16(
                            af[mh], bf[ih], aS[c][mh][ih], 0, 0, 0);
                #pragma unroll
                for (int ih = 0; ih < NIH; ++ih)
                    a0[c][ih] = __builtin_amdgcn_mfma_f32_16x16x32_f16(
                        ao, bf[ih], a0[c][ih], 0, 0, 0);
            }
        }
        if (base + CAP < L) __syncthreads();
    }

    // ---- tail: write F rows ----
    #pragma unroll
    for (int c = 0; c < 2; ++c) {
        const int d = n0 + w * 2 + c;
        const float iv = invc[d];
        _Float16* Fr = Fl + (size_t)(w * 2 + c) * LDK;
        #pragma unroll
        for (int mh = 0; mh < 2; ++mh)
            #pragma unroll
            for (int ih = 0; ih < NIH; ++ih)
                #pragma unroll
                for (int r = 0; r < 4; ++r)
                    Fr[32 * (ih * 16 + col) + mh * 16 + g4 + r] =
                        (_Float16)(aS[c][mh][ih][r] * iv);
        if (g4 == 0) {
            #pragma unroll
            for (int ih = 0; ih < NIH; ++ih)
                Fr[32 * CIN + ih * 16 + col] = (_Float16)(a0[c][ih][0] * iv);
        }
        if (lane >= CIN && lane < 2 * CIN)
            Fr[32 * CIN + lane] = xin16[(size_t)d * CIN + (lane - CIN)];
    }
    __syncthreads();

    // ---- Phase B: 8-way K-split MFMA (verified) ----
    const int o16 = col, g = lane >> 4;

    const _Float16* Arow = Fl + (size_t)o16 * LDK + g * 4;
    const _Float16* B0 = Wt + (size_t)o16 * K + g * 4;
    const _Float16* B1 = Wt + (size_t)(o16 + 16) * K + g * 4;

    f32x4 acc0 = {0.f, 0.f, 0.f, 0.f};
    f32x4 acc1 = {0.f, 0.f, 0.f, 0.f};

    const int sb = (steps * w) >> 3;
    const int se = (steps * (w + 1)) >> 3;
    #pragma unroll 2
    for (int s = sb; s < se; ++s) {
        const int k0 = s * 32;
        f16x4 alo = *(const f16x4*)(Arow + k0);
        f16x4 ahi = *(const f16x4*)(Arow + k0 + 16);
        f16x4 b0l = *(const f16x4*)(B0 + k0);
        f16x4 b0h = *(const f16x4*)(B0 + k0 + 16);
        f16x4 b1l = *(const f16x4*)(B1 + k0);
        f16x4 b1h = *(const f16x4*)(B1 + k0 + 16);
        f16x8 a, bb0, bb1;
        #pragma unroll
        for (int j = 0; j < 4; ++j) {
            a[j] = alo[j];  a[j + 4] = ahi[j];
            bb0[j] = b0l[j]; bb0[j + 4] = b0h[j];
            bb1[j] = b1l[j]; bb1[j + 4] = b1h[j];
        }
        acc0 = __builtin_amdgcn_mfma_f32_16x16x32_f16(a, bb0, acc0, 0, 0, 0);
        acc1 = __builtin_amdgcn_mfma_f32_16x16x32_f16(a, bb1, acc1, 0, 0, 0);
    }

    if (w > 0) {
        float* rw = red + (w - 1) * 512;
        #pragma unroll
        for (int r = 0; r < 4; ++r) {
            rw[(g * 4 + r) * 32 + o16]      = acc0[r];
            rw[(g * 4 + r) * 32 + 16 + o16] = acc1[r];
        }
    }
    __syncthreads();
    if (w == 0) {
        #pragma unroll
        for (int r = 0; r < 4; ++r) {
            const int ro = (g * 4 + r) * 32 + o16;
            #pragma unroll
            for (int p = 0; p < 7; ++p) {
                acc0[r] += red[p * 512 + ro];
                acc1[r] += red[p * 512 + ro + 16];
            }
        }
        const float bb0 = bias[o16], bb1 = bias[o16 + 16];
        const int nrow = n0 + g * 4;
        if (!DECODE) {
            _Float16* op = (_Float16*)outp;
            #pragma unroll
            for (int r = 0; r < 4; ++r) {
                op[(size_t)(nrow + r) * 32 + o16]      = (_Float16)silu_f(acc0[r] + bb0);
                op[(size_t)(nrow + r) * 32 + 16 + o16] = (_Float16)silu_f(acc1[r] + bb1);
            }
        } else {
            float* op = (float*)outp;
            const float w0 = dw[o16], w1v = dw[o16 + 16];
            const float dbv = db[0];
            #pragma unroll
            for (int r = 0; r < 4; ++r) {
                float p = silu_f(acc0[r] + bb0) * w0 + silu_f(acc1[r] + bb1) * w1v;
                p += __shfl_xor(p, 1);
                p += __shfl_xor(p, 2);
                p += __shfl_xor(p, 4);
                p += __shfl_xor(p, 8);
                if (o16 == 0) op[nrow + r] = p + dbv;
            }
        }
    }
}

// ---------------- launch ----------------

extern "C" void kernel_launch(void* const* d_in, const int* in_sizes, int n_in,
                              void* d_out, int out_size, void* d_ws, size_t ws_size,
                              hipStream_t stream) {
    const float* x      = (const float*)d_in[0];
    const int*   ei     = (const int*)d_in[1];
    const float* ew     = (const float*)d_in[2];
    const float* en1_w1 = (const float*)d_in[3];
    const float* en1_b1 = (const float*)d_in[4];
    const float* en1_w2 = (const float*)d_in[5];
    const float* en1_b2 = (const float*)d_in[6];
    const float* root1  = (const float*)d_in[7];
    const float* bias1  = (const float*)d_in[8];
    const float* en2_w1 = (const float*)d_in[9];
    const float* en2_b1 = (const float*)d_in[10];
    const float* en2_w2 = (const float*)d_in[11];
    const float* en2_b2 = (const float*)d_in[12];
    const float* root2  = (const float*)d_in[13];
    const float* bias2  = (const float*)d_in[14];
    const float* dec_w  = (const float*)d_in[15];
    const float* dec_b  = (const float*)d_in[16];
    float* out = (float*)d_out;
    (void)in_sizes; (void)n_in; (void)out_size; (void)ws_size;

    char* wp = (char*)d_ws;
    auto alloc = [&](size_t bytes) {
        char* p = wp;
        wp += (bytes + 255) & ~(size_t)255;
        return p;
    };
    unsigned int* histG = (unsigned int*)alloc((size_t)NB * NN * 4);  // 10.24 MB
    int*      cnt   = (int*)alloc((size_t)NN * 4);
    int*      off   = (int*)alloc((size_t)(NN + 1) * 4);
    float*    invc  = (float*)alloc((size_t)NN * 4);
    int2*     spair = (int2*)alloc((size_t)EE * 8);
    _Float16* h1h   = (_Float16*)alloc((size_t)NN * 32 * 2);
    _Float16* x16   = (_Float16*)alloc((size_t)NN * 16 * 2);
    _Float16* Wt1   = (_Float16*)alloc((size_t)17408 * 2);
    _Float16* Wt2   = (_Float16*)alloc((size_t)34816 * 2);

    const int build_blocks = (52224 + NN * 16 + 255) / 256;   // 1454
    prep_kernel<<<NB + build_blocks, 256, 0, stream>>>(
        ei, en1_w2, en1_b2, root1, en2_w2, en2_b2, root2, x,
        histG, Wt1, Wt2, x16);
    colscan_kernel<<<(NN + 255) / 256, 256, 0, stream>>>(histG, cnt, invc);
    scan_kernel<<<1, 1024, 0, stream>>>(cnt, off);
    scatter2_kernel<<<NB, 256, 0, stream>>>(ei, ew, off, histG, spair);

    auto f1 = fused_layer<16, false>;
    auto f2 = fused_layer<32, true>;
    (void)hipFuncSetAttribute((const void*)f1,
                              hipFuncAttributeMaxDynamicSharedMemorySize, 163840);
    (void)hipFuncSetAttribute((const void*)f2,
                              hipFuncAttributeMaxDynamicSharedMemorySize, 163840);

    const size_t lds1 = (size_t)16 * (34 * 16 + 4) * 2 + (448 * 4 + 192 * 16 * 2 + 192 * 64); // 37,760
    const size_t lds2 = (size_t)16 * (34 * 32 + 4) * 2 + (448 * 4 + 192 * 32 * 2 + 192 * 64); // 61,312

    fused_layer<16, false><<<NN / 16, 512, lds1, stream>>>(
        x16, (const int*)spair, off, invc, en1_w1, en1_b1, Wt1, bias1, h1h,
        nullptr, nullptr);
    fused_layer<32, true><<<NN / 16, 512, lds2, stream>>>(
        h1h, (const int*)spair, off, invc, en2_w1, en2_b1, Wt2, bias2, out,
        dec_w, dec_b);
}